// Round 16
// baseline (121.993 us; speedup 1.0000x reference)
//
#include <hip/hip_runtime.h>

// SigLIP contrastive loss:
//   logits = emb1 @ emb2^T / 0.07           [B,B], B=8192, D=1024
//   loss = ( sum_i softplus(-l_ii) + sum_{i!=j} softplus(l_ij) ) / B
// R16: exit the 2-phase regime (m233: 2-phase = 28% MFMA, exactly our R8-R15
// plateau; single-element fixes are null by the regime gate). m201-style
// fine-phase schedule on the proven fp8 data plane: 256x256, 8 waves
// (2Mx4N, per-wave 128x64, acc 128 VGPR), 128 KB LDS dbuf, 4 phases/K-tile,
// each {ds_reads || stage -> barrier -> lgkm0 -> setprio 8 MFMA -> barrier},
// B-frags held across phase pairs, vmcnt(0) after ph4 MFMAs (covered).

#define B_DIM 8192
#define K_DIM 1024
#define BKB 128                 // K bytes per K-tile
#define NT (K_DIM / BKB)        // 8 K-tiles
#define BRICK 16384             // one (128-row panel, K-tile) brick
#define PANEL_BYTES (NT * BRICK)
#define BUFSZ 65536             // LDS buffer: A 32K + B 32K

typedef int i32x4 __attribute__((ext_vector_type(4)));
typedef int i32x8 __attribute__((ext_vector_type(8)));
typedef float f32x4 __attribute__((ext_vector_type(4)));

// f32 -> fp8 e4m3 brick permutation (PANEL=128). One thread = 16 out bytes.
__device__ __forceinline__ void brick_store(const float* __restrict__ in,
                                            unsigned char* __restrict__ out,
                                            float scale, int i) {
  const int o = i * 16;
  const int b = o >> 14;                  // brick index
  const int p = b >> 3, t = b & 7;        // panel, K-tile
  const int w = o & (BRICK - 1);
  const int fb = w >> 11;
  const int h = (w >> 10) & 1;
  const int kch = (w >> 8) & 3;
  const int lr = (w >> 4) & 15;
  const int row = p * 128 + fb * 16 + lr;
  const int kb = t * 128 + kch * 32 + h * 16;
  const float4* src = (const float4*)(in + (size_t)row * K_DIM + kb);
  float4 v0 = src[0], v1 = src[1], v2 = src[2], v3 = src[3];
  unsigned w0 = 0, w1 = 0, w2 = 0, w3 = 0;
  w0 = __builtin_amdgcn_cvt_pk_fp8_f32(v0.x * scale, v0.y * scale, w0, 0);
  w0 = __builtin_amdgcn_cvt_pk_fp8_f32(v0.z * scale, v0.w * scale, w0, 1);
  w1 = __builtin_amdgcn_cvt_pk_fp8_f32(v1.x * scale, v1.y * scale, w1, 0);
  w1 = __builtin_amdgcn_cvt_pk_fp8_f32(v1.z * scale, v1.w * scale, w1, 1);
  w2 = __builtin_amdgcn_cvt_pk_fp8_f32(v2.x * scale, v2.y * scale, w2, 0);
  w2 = __builtin_amdgcn_cvt_pk_fp8_f32(v2.z * scale, v2.w * scale, w2, 1);
  w3 = __builtin_amdgcn_cvt_pk_fp8_f32(v3.x * scale, v3.y * scale, w3, 0);
  w3 = __builtin_amdgcn_cvt_pk_fp8_f32(v3.z * scale, v3.w * scale, w3, 1);
  *(uint4*)(out + o) = make_uint4(w0, w1, w2, w3);
}

__global__ __launch_bounds__(256) void cvt_fused(
    const float* __restrict__ e1, const float* __restrict__ e2,
    unsigned char* __restrict__ A8, unsigned char* __restrict__ B8,
    int nbA, float scaleA) {
  const int blk = blockIdx.x;
  if (blk < nbA)
    brick_store(e1, A8, scaleA, blk * 256 + threadIdx.x);
  else
    brick_store(e2, B8, 1.0f, (blk - nbA) * 256 + threadIdx.x);
}

// Cheap softplus accumulate: softplus(x) = max(x,0) + log(1+exp(-|x|)).
template <bool DIAG>
__device__ __forceinline__ float softplus_sum(const f32x4 (&acc)[8][4],
                                              int rbase, int cbase) {
  float lin = 0.f, cor = 0.f;
#pragma unroll
  for (int m = 0; m < 8; ++m) {
#pragma unroll
    for (int n = 0; n < 4; ++n) {
#pragma unroll
      for (int r = 0; r < 4; ++r) {
        float x = acc[m][n][r];
        if (DIAG) {
          int row = rbase + m * 16 + r;
          int col = cbase + n * 16;
          if (row == col) x = -x;  // diagonal: softplus(-l_ii)
        }
        lin += fmaxf(x, 0.f);
        cor += __logf(1.f + __expf(-fabsf(x)));
      }
    }
  }
  return lin + cor;
}

// Staging: 64 KB/K-tile. A region (32K): wave w covers slices w*4+q of the
// 2 bricks (panels 2*brow / 2*brow+1); B likewise with 2*bcol.
#define STAGEA(SB, Q, TI)                                                     \
  __builtin_amdgcn_global_load_lds(                                           \
      (const __attribute__((address_space(1))) void*)(const void*)(           \
          srcA + (TI) * BRICK + (Q) * 1024),                                  \
      (__attribute__((address_space(3))) void*)(void*)(                       \
          lds + (SB) + dA + (Q) * 1024),                                      \
      16, 0, 0)
#define STAGEB(SB, Q, TI)                                                     \
  __builtin_amdgcn_global_load_lds(                                           \
      (const __attribute__((address_space(1))) void*)(const void*)(           \
          srcB + (TI) * BRICK + (Q) * 1024),                                  \
      (__attribute__((address_space(3))) void*)(void*)(                       \
          lds + (SB) + dB + (Q) * 1024),                                      \
      16, 0, 0)
#define STG4A(SB, TI) \
  STAGEA(SB, 0, TI); STAGEA(SB, 1, TI); STAGEA(SB, 2, TI); STAGEA(SB, 3, TI)
#define STG4B(SB, TI) \
  STAGEB(SB, 0, TI); STAGEB(SB, 1, TI); STAGEB(SB, 2, TI); STAGEB(SB, 3, TI)

// Fragment reads: conflict-free lane*16 stride, 2x ds_read_b128 + combine.
// A frag (mh,i): region brick wr, frag row-block mh*4+i.
#define LDAF(OUT, RB, MH, I)                                                  \
  {                                                                           \
    const unsigned char* _b =                                                 \
        ldsL + ((RB) + wrbase + (((MH) * 4 + (I)) << 11));                    \
    i32x4 _lo = *(const i32x4*)(_b);                                          \
    i32x4 _hi = *(const i32x4*)(_b + 1024);                                   \
    OUT = __builtin_shufflevector(_lo, _hi, 0, 1, 2, 3, 4, 5, 6, 7);          \
  }
// B frag (nh,j): region brick wc>>1, frag col-block (wc&1)*4 + nh*2 + j.
#define LDBF(OUT, RB, NH, J)                                                  \
  {                                                                           \
    const unsigned char* _b =                                                 \
        ldsL + ((RB) + bcbase + (((NH) * 2 + (J)) << 11));                    \
    i32x4 _lo = *(const i32x4*)(_b);                                          \
    i32x4 _hi = *(const i32x4*)(_b + 1024);                                   \
    OUT = __builtin_shufflevector(_lo, _hi, 0, 1, 2, 3, 4, 5, 6, 7);          \
  }

#define MFMA1(AF, BF, M, N)                                                   \
  acc[M][N] = __builtin_amdgcn_mfma_scale_f32_16x16x128_f8f6f4(               \
      AF, BF, acc[M][N], 0, 0, 0, 127, 0, 127)

#define BARLG                                                                 \
  __builtin_amdgcn_s_barrier();                                               \
  asm volatile("s_waitcnt lgkmcnt(0)" ::: "memory");                          \
  __builtin_amdgcn_sched_barrier(0)

#define MF8(A0, A1, A2, A3, BB0, BB1, MH, NH)                                 \
  __builtin_amdgcn_s_setprio(1);                                              \
  MFMA1(A0, BB0, (MH)*4 + 0, (NH)*2 + 0);                                     \
  MFMA1(A0, BB1, (MH)*4 + 0, (NH)*2 + 1);                                     \
  MFMA1(A1, BB0, (MH)*4 + 1, (NH)*2 + 0);                                     \
  MFMA1(A1, BB1, (MH)*4 + 1, (NH)*2 + 1);                                     \
  MFMA1(A2, BB0, (MH)*4 + 2, (NH)*2 + 0);                                     \
  MFMA1(A2, BB1, (MH)*4 + 2, (NH)*2 + 1);                                     \
  MFMA1(A3, BB0, (MH)*4 + 3, (NH)*2 + 0);                                     \
  MFMA1(A3, BB1, (MH)*4 + 3, (NH)*2 + 1);                                     \
  __builtin_amdgcn_s_setprio(0)

// One K-tile: 4 phases (mh,nh) = (0,0),(1,0),(0,1),(1,1). B-frags for nh
// held in bf0/bf1 across the two mh phases. Stage A@ph1, B@ph2 into sbuf.
// vmcnt(0) after ph4's MFMAs (covered by ph3+ph4 ~1650 cyc), then barrier.
#define ITER(T)                                                               \
  {                                                                           \
    const int rb = ((T) & 1) * BUFSZ;                                         \
    const int sbuf = rb ^ BUFSZ;                                              \
    i32x8 bf0, bf1;                                                           \
    { /* ph1: (0,0) */                                                        \
      i32x8 af0, af1, af2, af3;                                               \
      LDBF(bf0, rb, 0, 0); LDBF(bf1, rb, 0, 1);                               \
      LDAF(af0, rb, 0, 0); LDAF(af1, rb, 0, 1);                               \
      LDAF(af2, rb, 0, 2); LDAF(af3, rb, 0, 3);                               \
      if ((T) < NT - 1) { STG4A(sbuf, (T) + 1); }                             \
      BARLG;                                                                  \
      MF8(af0, af1, af2, af3, bf0, bf1, 0, 0);                                \
      __builtin_amdgcn_s_barrier();                                           \
    }                                                                         \
    { /* ph2: (1,0) */                                                        \
      i32x8 af0, af1, af2, af3;                                               \
      LDAF(af0, rb, 1, 0); LDAF(af1, rb, 1, 1);                               \
      LDAF(af2, rb, 1, 2); LDAF(af3, rb, 1, 3);                               \
      if ((T) < NT - 1) { STG4B(sbuf, (T) + 1); }                             \
      BARLG;                                                                  \
      MF8(af0, af1, af2, af3, bf0, bf1, 1, 0);                                \
      __builtin_amdgcn_s_barrier();                                           \
    }                                                                         \
    { /* ph3: (0,1) */                                                        \
      i32x8 af0, af1, af2, af3;                                               \
      LDBF(bf0, rb, 1, 0); LDBF(bf1, rb, 1, 1);                               \
      LDAF(af0, rb, 0, 0); LDAF(af1, rb, 0, 1);                               \
      LDAF(af2, rb, 0, 2); LDAF(af3, rb, 0, 3);                               \
      BARLG;                                                                  \
      MF8(af0, af1, af2, af3, bf0, bf1, 0, 1);                                \
      __builtin_amdgcn_s_barrier();                                           \
    }                                                                         \
    { /* ph4: (1,1) */                                                        \
      i32x8 af0, af1, af2, af3;                                               \
      LDAF(af0, rb, 1, 0); LDAF(af1, rb, 1, 1);                               \
      LDAF(af2, rb, 1, 2); LDAF(af3, rb, 1, 3);                               \
      BARLG;                                                                  \
      MF8(af0, af1, af2, af3, bf0, bf1, 1, 1);                                \
      if ((T) < NT - 1) {                                                     \
        asm volatile("s_waitcnt vmcnt(0)" ::: "memory");                      \
      }                                                                       \
      __builtin_amdgcn_s_barrier();                                           \
      __builtin_amdgcn_sched_barrier(0);                                      \
    }                                                                         \
  }

__global__ __launch_bounds__(512, 1) void siglip_gemm(
    const unsigned char* __restrict__ A8,
    const unsigned char* __restrict__ B8,
    float* __restrict__ partials) {
  __shared__ unsigned char lds[2 * BUFSZ];  // 128 KB double buffer
  __shared__ float wsum[8];

  const int tid = threadIdx.x;
  const int wave = tid >> 6;
  const int lane = tid & 63;
  const int wr = wave >> 2;  // 0..1 -> 128-row strip
  const int wc = wave & 3;   // 0..3 -> 64-col strip
  const int brow = blockIdx.y;
  const int bcol = blockIdx.x;

  f32x4 acc[8][4];
#pragma unroll
  for (int m = 0; m < 8; ++m)
#pragma unroll
    for (int n = 0; n < 4; ++n) acc[m][n] = f32x4{0.f, 0.f, 0.f, 0.f};

  const unsigned char* srcA = A8 +
      (size_t)(2 * brow + (wave >> 2)) * PANEL_BYTES + (wave & 3) * 4096 +
      (lane << 4);
  const unsigned char* srcB = B8 +
      (size_t)(2 * bcol + (wave >> 2)) * PANEL_BYTES + (wave & 3) * 4096 +
      (lane << 4);
  const int dA = wave * 4096;            // A region [0, 32K)
  const int dB = 32768 + wave * 4096;    // B region [32K, 64K)
  const int wrbase = wr * 16384;                          // A frag base
  const int bcbase = 32768 + (wc >> 1) * 16384 + ((wc & 1) * 4) * 2048;
  const unsigned char* ldsL = lds + (lane << 4);          // per-lane base

  // Prologue: stage tile 0 into buf 0, drain, publish.
  STG4A(0, 0); STG4B(0, 0);
  asm volatile("s_waitcnt vmcnt(0)" ::: "memory");
  __builtin_amdgcn_s_barrier();
  __builtin_amdgcn_sched_barrier(0);

  ITER(0) ITER(1) ITER(2) ITER(3) ITER(4) ITER(5) ITER(6) ITER(7)

  // Epilogue. C/D 16x16 map: col = lane&15, row = (lane>>4)*4 + r.
  const int rbase = brow * 256 + wr * 128 + (lane >> 4) * 4;
  const int cbase = bcol * 256 + wc * 64 + (lane & 15);
  float lsum;
  if (brow == bcol)
    lsum = softplus_sum<true>(acc, rbase, cbase);
  else
    lsum = softplus_sum<false>(acc, rbase, cbase);

#pragma unroll
  for (int off = 32; off > 0; off >>= 1) lsum += __shfl_down(lsum, off);
  __syncthreads();
  if (lane == 0) wsum[wave] = lsum;
  __syncthreads();
  if (tid == 0) {
    float s = 0.f;
#pragma unroll
    for (int w = 0; w < 8; ++w) s += wsum[w];
    partials[blockIdx.y * gridDim.x + blockIdx.x] = s;
  }
}

__global__ void reduce_kernel(const float* __restrict__ partials, int n,
                              float* __restrict__ out) {
  __shared__ float s[256];
  float v = 0.f;
  for (int i = threadIdx.x; i < n; i += 256) v += partials[i];
  s[threadIdx.x] = v;
  __syncthreads();
  for (int off = 128; off > 0; off >>= 1) {
    if ((int)threadIdx.x < off) s[threadIdx.x] += s[threadIdx.x + off];
    __syncthreads();
  }
  if (threadIdx.x == 0) out[0] = s[0] / (float)B_DIM;
}

extern "C" void kernel_launch(void* const* d_in, const int* in_sizes, int n_in,
                              void* d_out, int out_size, void* d_ws, size_t ws_size,
                              hipStream_t stream) {
  const float* emb1 = (const float*)d_in[0];
  const float* emb2 = (const float*)d_in[1];

  unsigned char* A8 = (unsigned char*)d_ws;                // 8 MB (bricked)
  unsigned char* B8 = A8 + (size_t)B_DIM * K_DIM;          // 8 MB (bricked)
  float* partials = (float*)(B8 + (size_t)B_DIM * K_DIM);  // 4 KB

  const float INV_T = 1.0f / 0.07f;
  const int nbA = (B_DIM * K_DIM / 16) / 256;  // 2048 blocks per operand
  cvt_fused<<<2 * nbA, 256, 0, stream>>>(emb1, emb2, A8, B8, nbA, INV_T);

  dim3 grid(B_DIM / 256, B_DIM / 256);  // 32 x 32
  siglip_gemm<<<grid, 512, 0, stream>>>(A8, B8, partials);

  const int nparts = (B_DIM / 256) * (B_DIM / 256);
  reduce_kernel<<<1, 256, 0, stream>>>(partials, nparts, (float*)d_out);
}